// Round 6
// baseline (518.998 us; speedup 1.0000x reference)
//
#include <hip/hip_runtime.h>
#include <math.h>

#define LWI 96
#define LHI 96
#define HWD 384
#define NPIX 147456
#define LRPIX 9216
#define HID 256

typedef __attribute__((ext_vector_type(8))) _Float16 f16x8;
typedef __attribute__((ext_vector_type(4))) _Float16 f16x4;
typedef __attribute__((ext_vector_type(16))) float f32x16;

__device__ __forceinline__ float gelu_f(float x){
  return 0.5f*x*(1.0f + erff(x*0.70710678118654752440f));
}

// fast gelu: x*sigmoid(2*0.79788456*(x+0.044715x^3)); log2e folded -> exp2
__device__ __forceinline__ float gelu_fast(float x){
  float x2 = x*x;
  float u = x*(-2.3021181f - 0.1029443f*x2);
  float e = exp2f(u);
  return x * __builtin_amdgcn_rcpf(1.0f + e);
}

// jax.image.resize 'bilinear' (half-pixel, clamp) at scale 4
__device__ __forceinline__ float lr_up_at(const float* __restrict__ lr, int c, int y, int x){
  float sy = (y+0.5f)*0.25f - 0.5f;
  float sx = (x+0.5f)*0.25f - 0.5f;
  float fy = floorf(sy), fx = floorf(sx);
  float ty = sy - fy, tx = sx - fx;
  int y0 = (int)fy, x0 = (int)fx;
  int y0c = min(max(y0,0),LHI-1), y1c = min(max(y0+1,0),LHI-1);
  int x0c = min(max(x0,0),LWI-1), x1c = min(max(x0+1,0),LWI-1);
  const float* p = lr + c*LRPIX;
  float v00 = p[y0c*LWI+x0c], v01 = p[y0c*LWI+x1c];
  float v10 = p[y1c*LWI+x0c], v11 = p[y1c*LWI+x1c];
  return (1.f-ty)*((1.f-tx)*v00 + tx*v01) + ty*((1.f-tx)*v10 + tx*v11);
}

// naive conv (only used for Cin=3 first layer; K=27, cheap)
__global__ __launch_bounds__(256) void conv3x3_kernel(
    const float* __restrict__ in, const float* __restrict__ w,
    const float* __restrict__ b, float* __restrict__ out, int Cin){
  int tid = blockIdx.x*256 + threadIdx.x;
  int o = tid / LRPIX; int rem = tid - o*LRPIX;
  int y = rem / LWI;   int x = rem - y*LWI;
  int ou = __builtin_amdgcn_readfirstlane(o);
  float acc = b[ou];
  const float* wo = w + ou*Cin*9;
  for (int i=0;i<Cin;++i){
    const float* inp = in + i*LRPIX;
    #pragma unroll
    for (int dy=0;dy<3;++dy){
      int yy = y + dy - 1;
      bool yok = (yy>=0 && yy<LHI);
      #pragma unroll
      for (int dx=0;dx<3;++dx){
        int xx = x + dx - 1;
        float v = (yok && xx>=0 && xx<LWI) ? inp[yy*LWI+xx] : 0.0f;
        acc = fmaf(wo[i*9 + dy*3 + dx], v, acc);
      }
    }
  }
  out[tid] = gelu_f(acc);
}

// LDS-tiled conv3x3 Cin=64: 8x8 px tile x 16 oc per block; channel-last tile
__global__ __launch_bounds__(256) void conv3x3_tiled64(
    const float* __restrict__ in, const float* __restrict__ w,
    const float* __restrict__ b, float* __restrict__ out){
  __shared__ float tile[100*68];
  int t = threadIdx.x;
  int gx0 = blockIdx.x*8, gy0 = blockIdx.y*8;
  int wv = t >> 6, lane = t & 63;
  for (int ic = wv; ic < 64; ic += 4){
    const float* inc = in + ic*LRPIX;
    #pragma unroll
    for (int h = 0; h < 2; ++h){
      int sp = lane + h*64;
      if (sp < 100){
        int ly = (sp*205)>>11; int lx = sp - ly*10;
        int gy = gy0 - 1 + ly, gx = gx0 - 1 + lx;
        float v = (gy>=0 && gy<LHI && gx>=0 && gx<LWI) ? inc[gy*LWI+gx] : 0.f;
        tile[sp*68 + ic] = v;
      }
    }
  }
  __syncthreads();

  int px = lane; int y = px >> 3; int x = px & 7;
  int oc0 = blockIdx.z*16 + wv*4;
  float acc0=b[oc0], acc1=b[oc0+1], acc2=b[oc0+2], acc3=b[oc0+3];
  const float* w0p = w + (oc0+0)*576;
  const float* w1p = w + (oc0+1)*576;
  const float* w2p = w + (oc0+2)*576;
  const float* w3p = w + (oc0+3)*576;
  for (int icq = 0; icq < 16; ++icq){
    float4 v[9];
    #pragma unroll
    for (int dy=0; dy<3; ++dy)
      #pragma unroll
      for (int dx=0; dx<3; ++dx)
        v[dy*3+dx] = *(const float4*)&tile[((y+dy)*10 + (x+dx))*68 + icq*4];
    #pragma unroll
    for (int tap=0; tap<9; ++tap){
      float4 vv = v[tap];
      const float* vp = (const float*)&vv;
      #pragma unroll
      for (int c=0;c<4;++c){
        int wi = (icq*4+c)*9 + tap;
        float val = vp[c];
        acc0 = fmaf(w0p[wi], val, acc0);
        acc1 = fmaf(w1p[wi], val, acc1);
        acc2 = fmaf(w2p[wi], val, acc2);
        acc3 = fmaf(w3p[wi], val, acc3);
      }
    }
  }
  int gout = (gy0+y)*LWI + gx0 + x;
  out[(oc0+0)*LRPIX + gout] = gelu_f(acc0);
  out[(oc0+1)*LRPIX + gout] = gelu_f(acc1);
  out[(oc0+2)*LRPIX + gout] = gelu_f(acc2);
  out[(oc0+3)*LRPIX + gout] = gelu_f(acc3);
}

__global__ __launch_bounds__(256) void conv1x1_kernel(
    const float* __restrict__ in, const float* __restrict__ w,
    const float* __restrict__ b, float* __restrict__ out,
    int wstride, int dogelu){
  int tid = blockIdx.x*256 + threadIdx.x;
  int o = tid / LRPIX; int p = tid - o*LRPIX;
  int ou = __builtin_amdgcn_readfirstlane(o);
  float acc = b[ou];
  const float* wo = w + ou*wstride;
  for (int i=0;i<64;++i) acc = fmaf(wo[i], in[i*LRPIX+p], acc);
  out[tid] = dogelu ? gelu_f(acc) : acc;
}

// ---- pack weights (f32 [K][N] row-major) into f16 fragment-major order ----
__global__ __launch_bounds__(256) void pack_weights(
  const float* __restrict__ mw0, const float* __restrict__ mw1,
  const float* __restrict__ mw2, const float* __restrict__ mw3,
  const float* __restrict__ mw4, const float* __restrict__ hkw,
  const float* __restrict__ hgw,
  const float* __restrict__ mb0, const float* __restrict__ mb1,
  const float* __restrict__ mb2, const float* __restrict__ mb3,
  const float* __restrict__ mb4, const float* __restrict__ hkb,
  const float* __restrict__ hgb,
  _Float16* __restrict__ WB, float* __restrict__ biasAll)
{
  int i = blockIdx.x*256 + threadIdx.x;
  if (i < 356352){
    int layer, local;
    if (i < 28672){ layer = 0; local = i; }
    else { layer = 1 + ((i-28672)>>16); local = (i-28672)&65535; }
    int ks = local >> 12; int r = local & 4095;
    int cb = r >> 9; int s2 = r & 511; int slot = s2 >> 3; int e = s2 & 7;
    int col = cb*32 + (slot & 31); int g = slot >> 5;
    int k = ks*16 + g*8 + e;
    float v = 0.f;
    if (layer == 0){ if (k < 106) v = mw0[k*256+col]; }
    else if (layer == 1) v = mw1[k*256+col];
    else if (layer == 2) v = mw2[k*256+col];
    else if (layer == 3) v = mw3[k*256+col];
    else if (layer == 4) v = mw4[k*256+col];
    else { if (col < 196) v = hkw[k*196+col]; else if (col < 200) v = hgw[k*4+col-196]; }
    WB[i] = (_Float16)v;
  } else if (i < 356352+1536){
    int j = i - 356352; int layer = j>>8; int col = j&255;
    float v = 0.f;
    if (layer==0) v=mb0[col]; else if (layer==1) v=mb1[col]; else if(layer==2) v=mb2[col];
    else if(layer==3) v=mb3[col]; else if(layer==4) v=mb4[col];
    else { if (col<196) v=hkb[col]; else if(col<200) v=hgb[col-196]; }
    biasAll[j] = v;
  }
}

// MFMA pass: wave w computes feats [32w,32w+32) x 64 px over K=16*NKS
template<int NKS>
__device__ __forceinline__ void mlp_pass(const _Float16* __restrict__ Wl,
    const _Float16* __restrict__ buf, int lane, int w, f32x16 (&acc)[2]){
  acc[0] = f32x16{}; acc[1] = f32x16{};
  #pragma unroll
  for (int ks=0; ks<NKS; ++ks){
    f16x8 a = *(const f16x8*)(Wl + (ks*8+w)*512 + lane*8);
    const _Float16* bp = buf + ks*1024 + lane*8;
    f16x8 b0 = *(const f16x8*)(bp);
    f16x8 b1 = *(const f16x8*)(bp + 512);
    acc[0] = __builtin_amdgcn_mfma_f32_32x32x16_f16(a,b0,acc[0],0,0,0);
    acc[1] = __builtin_amdgcn_mfma_f32_32x32x16_f16(a,b1,acc[1],0,0,0);
  }
}

// ---- MFMA MLP v3: 64 px/block, 8 waves, 32KB in-place LDS, 3+ blocks/CU ----
// act addr(k,p) = ((k>>4)*2 + (p>>5))*512 + ((p&31)+32*((k>>3)&1))*8 + (k&7)
__global__ __launch_bounds__(512,6) void mlp_mfma3_kernel(
  const float* __restrict__ feat, const float* __restrict__ lr,
  const _Float16* __restrict__ WB, const float* __restrict__ biasAll,
  float* __restrict__ sr)
{
  __shared__ _Float16 buf[16384];   // 32KB
  const int t = threadIdx.x;
  const int lane = t & 63;
  const int w = __builtin_amdgcn_readfirstlane(t >> 6);   // 0..7
  const int p31 = lane & 31; const int hi = lane >> 5;

  // ---- z build: q = wave, p = lane ----
  {
    const int p = lane; const int q = w;
    const int px = blockIdx.x*64 + p;
    const int y = px / HWD; const int x = px - y*HWD;
    float lx = (x+0.5f)*0.25f - 0.5f;
    float ly = (y+0.5f)*0.25f - 0.5f;
    float cxf = fminf(fmaxf(rintf(lx),0.f),95.f);
    float cyf = fminf(fmaxf(rintf(ly),0.f),95.f);
    int base = (int)cyf*LWI + (int)cxf;
    auto zwrite = [&](int k, float v){
      buf[((k>>4)*2 + (p>>5))*512 + ((p&31) + 32*((k>>3)&1))*8 + (k&7)] = (_Float16)v;
    };
    if (q < 2){
      #pragma unroll
      for (int j=0;j<32;++j){ int c=q*32+j; zwrite(c, feat[c*LRPIX+base]); }
    } else if (q == 2){
      float xn = (x+0.5f)/384.0f*2.0f - 1.0f;
      float s = sinf(xn*3.14159265358979323846f);
      float c = cosf(xn*3.14159265358979323846f);
      #pragma unroll
      for (int b=0;b<10;++b){
        zwrite(64+4*b+0, s); zwrite(64+4*b+1, c);
        float s2 = 2.f*s*c; float c2 = 1.f - 2.f*s*s;
        s=s2; c=c2;
      }
      zwrite(104, lx-cxf); zwrite(105, ly-cyf);
    } else if (q == 3){
      float yn = (y+0.5f)/384.0f*2.0f - 1.0f;
      float s = sinf(yn*3.14159265358979323846f);
      float c = cosf(yn*3.14159265358979323846f);
      #pragma unroll
      for (int b=0;b<10;++b){
        zwrite(64+4*b+2, s); zwrite(64+4*b+3, c);
        float s2 = 2.f*s*c; float c2 = 1.f - 2.f*s*s;
        s=s2; c=c2;
      }
    } else if (q == 4){
      #pragma unroll
      for (int k=106;k<112;++k) zwrite(k, 0.f);
    }
  }
  __syncthreads();

  // ---- 5 hidden layers, in-place ----
  #pragma unroll 1
  for (int L=0; L<5; ++L){
    static const int WOFFS[5] = {0,28672,94208,159744,225280};
    f32x16 acc[2];
    if (L==0) mlp_pass<7>(WB, buf, lane, w, acc);
    else      mlp_pass<16>(WB + WOFFS[L], buf, lane, w, acc);
    __syncthreads();
    const float* Bl = biasAll + L*256;
    #pragma unroll
    for (int q2=0;q2<4;++q2){
      float4 bs = *(const float4*)&Bl[w*32 + q2*8 + 4*hi];
      const float* bp2 = (const float*)&bs;
      int ks2 = w*2 + (q2>>1); int g2 = q2&1;
      _Float16* dst = buf + (ks2*2)*512 + (p31 + 32*g2)*8 + 4*hi;
      #pragma unroll
      for (int pb=0;pb<2;++pb){
        f16x4 o;
        #pragma unroll
        for (int r=0;r<4;++r) o[r] = (_Float16)gelu_fast(acc[pb][q2*4+r] + bp2[r]);
        *(f16x4*)(dst + pb*512) = o;
      }
    }
    __syncthreads();
  }

  // ---- heads: K=256 -> 200 rows; klog f16 overlay [f][72] ----
  {
    f32x16 acc[2];
    if (w < 7) mlp_pass<16>(WB + 290816, buf, lane, w, acc);
    __syncthreads();   // reads done before klog overlay writes
    if (w < 7){
      #pragma unroll
      for (int reg=0;reg<16;++reg){
        int f = w*32 + (reg&3) + 8*(reg>>2) + 4*hi;
        if (f < 200){
          float bias = biasAll[1280 + f];
          buf[f*72 + p31]      = (_Float16)(acc[0][reg] + bias);
          buf[f*72 + 32 + p31] = (_Float16)(acc[1][reg] + bias);
        }
      }
    }
  }
  __syncthreads();

  // ---- softmax per head + gate softmax; in-place gated weights (f16) ----
  if (t < 256){
    const int p = t & 63; const int hd = t >> 6;
    auto KL = [&](int col)->float { return (float)buf[col*72 + p]; };
    float g0=KL(196),g1=KL(197),g2=KL(198),g3=KL(199);
    float gm = fmaxf(fmaxf(g0,g1),fmaxf(g2,g3));
    float e0=__expf(g0-gm),e1=__expf(g1-gm),e2=__expf(g2-gm),e3=__expf(g3-gm);
    float gate = ((hd==0)?e0:(hd==1)?e1:(hd==2)?e2:e3)/(e0+e1+e2+e3);
    float m = -1e30f;
    #pragma unroll
    for (int k=0;k<49;++k) m = fmaxf(m, KL(hd*49+k));
    float s = 0.f;
    float ev[49];
    #pragma unroll
    for (int k=0;k<49;++k){ float e=__expf(KL(hd*49+k)-m); s+=e; ev[k]=e; }
    float sc = gate/s;
    #pragma unroll
    for (int k=0;k<49;++k) buf[(hd*49+k)*72 + p] = (_Float16)(ev[k]*sc);
  }
  __syncthreads();

  // ---- apply mixed 7x7 kernel ----
  if (t < 192){
    const int c = t >> 6; const int p = t & 63;
    const int px = blockIdx.x*64 + p;
    const int y = px / HWD; const int x = px - y*HWD;
    float lx = (x+0.5f)*0.25f - 0.5f;
    float ly = (y+0.5f)*0.25f - 0.5f;
    int cxi = (int)fminf(fmaxf(rintf(lx),0.f),95.f);
    int cyi = (int)fminf(fmaxf(rintf(ly),0.f),95.f);
    const float* lrc = lr + c*LRPIX;
    float acc = 0.f;
    #pragma unroll
    for (int k=0;k<49;++k){
      float km = (float)buf[k*72+p] + (float)buf[(49+k)*72+p]
               + (float)buf[(98+k)*72+p] + (float)buf[(147+k)*72+p];
      int oy = k/7 - 3, ox = k - (k/7)*7 - 3;
      int nyy = min(max(cyi+oy,0),95), nxx = min(max(cxi+ox,0),95);
      acc = fmaf(km, lrc[nyy*LWI+nxx], acc);
    }
    sr[c*NPIX + px] = acc;
  }
}

// ---- refiner v2: one block per (16x16 tile, group); groups independent ----
__global__ __launch_bounds__(256) void refiner_group_kernel(
  const float* __restrict__ lr, const float* __restrict__ srg,
  const float* __restrict__ w0, const float* __restrict__ b0,
  const float* __restrict__ w1, const float* __restrict__ b1,
  const float* __restrict__ w2, const float* __restrict__ b2,
  float* __restrict__ resW)
{
  __shared__ float x6s[2][22][26];
  __shared__ float r1a[16][20][20];
  __shared__ float r1b[16][18][20];
  const int g = blockIdx.z;
  const int tid = threadIdx.x;
  const int gx0 = blockIdx.x*16, gy0 = blockIdx.y*16;

  for (int i = tid; i < 2*22*22; i += 256){
    int ic = i / 484; int rem = i - ic*484; int yy = rem / 22; int xx = rem - yy*22;
    int ch = g*2 + ic;
    int gy = gy0 - 3 + yy, gx = gx0 - 3 + xx;
    float v = 0.f;
    if (gy>=0 && gy<HWD && gx>=0 && gx<HWD){
      int c = (ch<3)?ch:(ch-3);
      float lu = lr_up_at(lr, c, gy, gx);
      v = (ch < 3) ? lu : (srg[c*NPIX + gy*HWD + gx] - lu);
    }
    x6s[ic][yy][xx] = v;
  }
  __syncthreads();

  for (int task = tid; task < 320; task += 256){
    int o = task / 20; int yy = task - o*20;
    int og = g*16 + o;
    float bias = b0[og];
    float acc[20];
    #pragma unroll
    for (int j=0;j<20;++j) acc[j] = bias;
    #pragma unroll
    for (int ic=0; ic<2; ++ic){
      #pragma unroll
      for (int dyy=0; dyy<3; ++dyy){
        float row[22];
        #pragma unroll
        for (int j=0;j<22;++j) row[j] = x6s[ic][yy+dyy][j];
        #pragma unroll
        for (int dxx=0; dxx<3; ++dxx){
          float wv = w0[((og*2+ic)*3+dyy)*3+dxx];
          #pragma unroll
          for (int j=0;j<20;++j) acc[j] = fmaf(wv, row[j+dxx], acc[j]);
        }
      }
    }
    int gyy = gy0 - 2 + yy;
    bool rok = (gyy>=0 && gyy<HWD);
    #pragma unroll
    for (int j=0;j<20;++j){
      int gxx = gx0 - 2 + j;
      r1a[o][yy][j] = (rok && gxx>=0 && gxx<HWD) ? gelu_f(acc[j]) : 0.f;
    }
  }
  __syncthreads();

  for (int task = tid; task < 288; task += 256){
    int o = task / 18; int yy = task - o*18;
    int og = g*16 + o;
    float bias = b1[og];
    float acc[18];
    #pragma unroll
    for (int j=0;j<18;++j) acc[j] = bias;
    for (int ic=0; ic<16; ++ic){
      #pragma unroll
      for (int dyy=0; dyy<3; ++dyy){
        float row[20];
        #pragma unroll
        for (int q=0;q<5;++q)
          *(float4*)&row[q*4] = *(const float4*)&r1a[ic][yy+dyy][q*4];
        #pragma unroll
        for (int dxx=0; dxx<3; ++dxx){
          float wv = w1[((og*16+ic)*3+dyy)*3+dxx];
          #pragma unroll
          for (int j=0;j<18;++j) acc[j] = fmaf(wv, row[j+dxx], acc[j]);
        }
      }
    }
    int gyy = gy0 - 1 + yy;
    bool rok = (gyy>=0 && gyy<HWD);
    #pragma unroll
    for (int j=0;j<18;++j){
      int gxx = gx0 - 1 + j;
      r1b[o][yy][j] = (rok && gxx>=0 && gxx<HWD) ? gelu_f(acc[j]) : 0.f;
    }
  }
  __syncthreads();

  {
    int ty = tid >> 4, tx = tid & 15;
    float a = b2[g];
    for (int ic=0; ic<16; ++ic){
      #pragma unroll
      for (int dyy=0; dyy<3; ++dyy){
        #pragma unroll
        for (int dxx=0; dxx<3; ++dxx){
          a = fmaf(w2[((g*16+ic)*3+dyy)*3+dxx], r1b[ic][ty+dyy][tx+dxx], a);
        }
      }
    }
    resW[g*NPIX + (gy0+ty)*HWD + gx0+tx] = a;
  }
}

// gray-residual fusion: out = clip(lr_up + gray(sr+res) - gray(lr_up))
__global__ __launch_bounds__(256) void fuse_kernel(
  const float* __restrict__ lr, const float* __restrict__ srg,
  const float* __restrict__ resW, float* __restrict__ out)
{
  int p = blockIdx.x*256 + threadIdx.x;
  int y = p / HWD, x = p - y*HWD;
  float lu[3];
  float d = 0.f;
  const float cf0=0.2989f, cf1=0.587f, cf2=0.114f;
  lu[0] = lr_up_at(lr, 0, y, x);
  lu[1] = lr_up_at(lr, 1, y, x);
  lu[2] = lr_up_at(lr, 2, y, x);
  d += cf0*(srg[0*NPIX+p] + resW[0*NPIX+p] - lu[0]);
  d += cf1*(srg[1*NPIX+p] + resW[1*NPIX+p] - lu[1]);
  d += cf2*(srg[2*NPIX+p] + resW[2*NPIX+p] - lu[2]);
  #pragma unroll
  for (int c=0;c<3;++c){
    float o_ = lu[c] + d;
    out[c*NPIX + p] = fminf(fmaxf(o_, 0.f), 1.f);
  }
}

extern "C" void kernel_launch(void* const* d_in, const int* in_sizes, int n_in,
                              void* d_out, int out_size, void* d_ws, size_t ws_size,
                              hipStream_t stream){
  const float* lr  = (const float*)d_in[0];
  const float* ew0 = (const float*)d_in[1];  const float* eb0 = (const float*)d_in[2];
  const float* ew1 = (const float*)d_in[3];  const float* eb1 = (const float*)d_in[4];
  const float* ew2 = (const float*)d_in[5];  const float* eb2 = (const float*)d_in[6];
  const float* ew3 = (const float*)d_in[7];  const float* eb3 = (const float*)d_in[8];
  const float* cw0 = (const float*)d_in[9];  const float* cb0 = (const float*)d_in[10];
  const float* cw1 = (const float*)d_in[11]; const float* cb1 = (const float*)d_in[12];
  const float* mw0 = (const float*)d_in[13]; const float* mb0 = (const float*)d_in[14];
  const float* mw1 = (const float*)d_in[15]; const float* mb1 = (const float*)d_in[16];
  const float* mw2 = (const float*)d_in[17]; const float* mb2 = (const float*)d_in[18];
  const float* mw3 = (const float*)d_in[19]; const float* mb3 = (const float*)d_in[20];
  const float* mw4 = (const float*)d_in[21]; const float* mb4 = (const float*)d_in[22];
  const float* hkw = (const float*)d_in[23]; const float* hkb = (const float*)d_in[24];
  const float* hgw = (const float*)d_in[25]; const float* hgb = (const float*)d_in[26];
  const float* rw0 = (const float*)d_in[27]; const float* rb0 = (const float*)d_in[28];
  const float* rw1 = (const float*)d_in[29]; const float* rb1 = (const float*)d_in[30];
  const float* rw2 = (const float*)d_in[31]; const float* rb2 = (const float*)d_in[32];

  float* ws = (float*)d_ws;
  float* f0  = ws;                     // [64][96][96]; reused as resW after convs
  float* f1  = ws + 589824;            // [64][96][96]
  float* srp = ws + 2*589824;          // [3][384][384]
  _Float16* WB = (_Float16*)(ws + 1622016);   // 356352 f16
  float* biasAll = ws + 1622016 + 178176;     // 1536 f32
  float* resW = f0;                    // free after conv1x1 chain

  pack_weights<<<1398,256,0,stream>>>(mw0,mw1,mw2,mw3,mw4,hkw,hgw,
      mb0,mb1,mb2,mb3,mb4,hkb,hgb, WB, biasAll);

  conv3x3_kernel<<<2304,256,0,stream>>>(lr, ew0, eb0, f0, 3);
  conv3x3_tiled64<<<dim3(12,12,4),256,0,stream>>>(f0, ew1, eb1, f1);
  conv3x3_tiled64<<<dim3(12,12,4),256,0,stream>>>(f1, ew2, eb2, f0);
  conv3x3_tiled64<<<dim3(12,12,4),256,0,stream>>>(f0, ew3, eb3, f1);
  conv1x1_kernel<<<2304,256,0,stream>>>(f1, cw0, cb0, f0, 66, 1);
  conv1x1_kernel<<<2304,256,0,stream>>>(f0, cw1, cb1, f1, 64, 0);

  mlp_mfma3_kernel<<<2304,512,0,stream>>>(f1, lr, WB, biasAll, srp);

  refiner_group_kernel<<<dim3(24,24,3),256,0,stream>>>(lr, srp,
      rw0,rb0, rw1,rb1, rw2,rb2, resW);
  fuse_kernel<<<576,256,0,stream>>>(lr, srp, resW, (float*)d_out);
}

// Round 7
// 509.982 us; speedup vs baseline: 1.0177x; 1.0177x over previous
//
#include <hip/hip_runtime.h>
#include <hip/hip_fp16.h>
#include <math.h>

#define LWI 96
#define LHI 96
#define HWD 384
#define NPIX 147456
#define LRPIX 9216
#define HID 256

typedef __attribute__((ext_vector_type(8))) _Float16 f16x8;
typedef __attribute__((ext_vector_type(4))) _Float16 f16x4;
typedef __attribute__((ext_vector_type(16))) float f32x16;

__device__ __forceinline__ float gelu_f(float x){
  return 0.5f*x*(1.0f + erff(x*0.70710678118654752440f));
}

// fast gelu f32 path (convs): x*sigmoid-form, exp2 with folded log2e
__device__ __forceinline__ float gelu_fast(float x){
  float x2 = x*x;
  float u = x*(-2.3021181f - 0.1029443f*x2);
  float e = exp2f(u);
  return x * __builtin_amdgcn_rcpf(1.0f + e);
}

// packed-f16 gelu pair: f32 cubic arg, f16 exp2/rcp tail (err ~5e-4 abs)
__device__ __forceinline__ void gelu2pk(float x0, float x1, _Float16* out){
  float u0 = x0*(-2.3021181f - 0.1029443f*(x0*x0));
  float u1 = x1*(-2.3021181f - 0.1029443f*(x1*x1));
  __half2 u = __floats2half2_rn(u0, u1);
  __half2 e = h2exp2(u);
  __half2 d = __hadd2(e, __float2half2_rn(1.0f));
  __half2 r = h2rcp(d);
  __half2 xh = __floats2half2_rn(x0, x1);
  __half2 g = __hmul2(xh, r);
  out[0] = ((_Float16*)&g)[0];
  out[1] = ((_Float16*)&g)[1];
}

// jax.image.resize 'bilinear' (half-pixel, clamp) at scale 4
__device__ __forceinline__ float lr_up_at(const float* __restrict__ lr, int c, int y, int x){
  float sy = (y+0.5f)*0.25f - 0.5f;
  float sx = (x+0.5f)*0.25f - 0.5f;
  float fy = floorf(sy), fx = floorf(sx);
  float ty = sy - fy, tx = sx - fx;
  int y0 = (int)fy, x0 = (int)fx;
  int y0c = min(max(y0,0),LHI-1), y1c = min(max(y0+1,0),LHI-1);
  int x0c = min(max(x0,0),LWI-1), x1c = min(max(x0+1,0),LWI-1);
  const float* p = lr + c*LRPIX;
  float v00 = p[y0c*LWI+x0c], v01 = p[y0c*LWI+x1c];
  float v10 = p[y1c*LWI+x0c], v11 = p[y1c*LWI+x1c];
  return (1.f-ty)*((1.f-tx)*v00 + tx*v01) + ty*((1.f-tx)*v10 + tx*v11);
}

// naive conv (only used for Cin=3 first layer; K=27, cheap)
__global__ __launch_bounds__(256) void conv3x3_kernel(
    const float* __restrict__ in, const float* __restrict__ w,
    const float* __restrict__ b, float* __restrict__ out, int Cin){
  int tid = blockIdx.x*256 + threadIdx.x;
  int o = tid / LRPIX; int rem = tid - o*LRPIX;
  int y = rem / LWI;   int x = rem - y*LWI;
  int ou = __builtin_amdgcn_readfirstlane(o);
  float acc = b[ou];
  const float* wo = w + ou*Cin*9;
  for (int i=0;i<Cin;++i){
    const float* inp = in + i*LRPIX;
    #pragma unroll
    for (int dy=0;dy<3;++dy){
      int yy = y + dy - 1;
      bool yok = (yy>=0 && yy<LHI);
      #pragma unroll
      for (int dx=0;dx<3;++dx){
        int xx = x + dx - 1;
        float v = (yok && xx>=0 && xx<LWI) ? inp[yy*LWI+xx] : 0.0f;
        acc = fmaf(wo[i*9 + dy*3 + dx], v, acc);
      }
    }
  }
  out[tid] = gelu_f(acc);
}

// LDS-tiled conv3x3 Cin=64: 8x8 px tile x 16 oc per block; channel-last tile
__global__ __launch_bounds__(256) void conv3x3_tiled64(
    const float* __restrict__ in, const float* __restrict__ w,
    const float* __restrict__ b, float* __restrict__ out){
  __shared__ float tile[100*68];
  int t = threadIdx.x;
  int gx0 = blockIdx.x*8, gy0 = blockIdx.y*8;
  int wv = t >> 6, lane = t & 63;
  for (int ic = wv; ic < 64; ic += 4){
    const float* inc = in + ic*LRPIX;
    #pragma unroll
    for (int h = 0; h < 2; ++h){
      int sp = lane + h*64;
      if (sp < 100){
        int ly = (sp*205)>>11; int lx = sp - ly*10;
        int gy = gy0 - 1 + ly, gx = gx0 - 1 + lx;
        float v = (gy>=0 && gy<LHI && gx>=0 && gx<LWI) ? inc[gy*LWI+gx] : 0.f;
        tile[sp*68 + ic] = v;
      }
    }
  }
  __syncthreads();

  int px = lane; int y = px >> 3; int x = px & 7;
  int oc0 = blockIdx.z*16 + wv*4;
  float acc0=b[oc0], acc1=b[oc0+1], acc2=b[oc0+2], acc3=b[oc0+3];
  const float* w0p = w + (oc0+0)*576;
  const float* w1p = w + (oc0+1)*576;
  const float* w2p = w + (oc0+2)*576;
  const float* w3p = w + (oc0+3)*576;
  for (int icq = 0; icq < 16; ++icq){
    float4 v[9];
    #pragma unroll
    for (int dy=0; dy<3; ++dy)
      #pragma unroll
      for (int dx=0; dx<3; ++dx)
        v[dy*3+dx] = *(const float4*)&tile[((y+dy)*10 + (x+dx))*68 + icq*4];
    #pragma unroll
    for (int tap=0; tap<9; ++tap){
      float4 vv = v[tap];
      const float* vp = (const float*)&vv;
      #pragma unroll
      for (int c=0;c<4;++c){
        int wi = (icq*4+c)*9 + tap;
        float val = vp[c];
        acc0 = fmaf(w0p[wi], val, acc0);
        acc1 = fmaf(w1p[wi], val, acc1);
        acc2 = fmaf(w2p[wi], val, acc2);
        acc3 = fmaf(w3p[wi], val, acc3);
      }
    }
  }
  int gout = (gy0+y)*LWI + gx0 + x;
  out[(oc0+0)*LRPIX + gout] = gelu_f(acc0);
  out[(oc0+1)*LRPIX + gout] = gelu_f(acc1);
  out[(oc0+2)*LRPIX + gout] = gelu_f(acc2);
  out[(oc0+3)*LRPIX + gout] = gelu_f(acc3);
}

__global__ __launch_bounds__(256) void conv1x1_kernel(
    const float* __restrict__ in, const float* __restrict__ w,
    const float* __restrict__ b, float* __restrict__ out,
    int wstride, int dogelu){
  int tid = blockIdx.x*256 + threadIdx.x;
  int o = tid / LRPIX; int p = tid - o*LRPIX;
  int ou = __builtin_amdgcn_readfirstlane(o);
  float acc = b[ou];
  const float* wo = w + ou*wstride;
  for (int i=0;i<64;++i) acc = fmaf(wo[i], in[i*LRPIX+p], acc);
  out[tid] = dogelu ? gelu_f(acc) : acc;
}

// ---- pack weights (f32 [K][N] row-major) into f16 fragment-major order ----
__global__ __launch_bounds__(256) void pack_weights(
  const float* __restrict__ mw0, const float* __restrict__ mw1,
  const float* __restrict__ mw2, const float* __restrict__ mw3,
  const float* __restrict__ mw4, const float* __restrict__ hkw,
  const float* __restrict__ hgw,
  const float* __restrict__ mb0, const float* __restrict__ mb1,
  const float* __restrict__ mb2, const float* __restrict__ mb3,
  const float* __restrict__ mb4, const float* __restrict__ hkb,
  const float* __restrict__ hgb,
  _Float16* __restrict__ WB, float* __restrict__ biasAll)
{
  int i = blockIdx.x*256 + threadIdx.x;
  if (i < 356352){
    int layer, local;
    if (i < 28672){ layer = 0; local = i; }
    else { layer = 1 + ((i-28672)>>16); local = (i-28672)&65535; }
    int ks = local >> 12; int r = local & 4095;
    int cb = r >> 9; int s2 = r & 511; int slot = s2 >> 3; int e = s2 & 7;
    int col = cb*32 + (slot & 31); int g = slot >> 5;
    int k = ks*16 + g*8 + e;
    float v = 0.f;
    if (layer == 0){ if (k < 106) v = mw0[k*256+col]; }
    else if (layer == 1) v = mw1[k*256+col];
    else if (layer == 2) v = mw2[k*256+col];
    else if (layer == 3) v = mw3[k*256+col];
    else if (layer == 4) v = mw4[k*256+col];
    else { if (col < 196) v = hkw[k*196+col]; else if (col < 200) v = hgw[k*4+col-196]; }
    WB[i] = (_Float16)v;
  } else if (i < 356352+1536){
    int j = i - 356352; int layer = j>>8; int col = j&255;
    float v = 0.f;
    if (layer==0) v=mb0[col]; else if (layer==1) v=mb1[col]; else if(layer==2) v=mb2[col];
    else if(layer==3) v=mb3[col]; else if(layer==4) v=mb4[col];
    else { if (col<196) v=hkb[col]; else if(col<200) v=hgb[col-196]; }
    biasAll[j] = v;
  }
}

// ---- MFMA MLP v4: 128 px/block, 8 waves, double-buffer, 1 barrier/layer ----
// act addr(k,p) in a 32KB half: ((k>>4)*4 + (p>>5))*512 + ((p&31)+32*((k>>3)&1))*8 + (k&7)
// wave w owns feature block [32w, 32w+32)
__global__ __launch_bounds__(512,4) void mlp_mfma4_kernel(
  const float* __restrict__ feat, const float* __restrict__ lr,
  const _Float16* __restrict__ WB, const float* __restrict__ biasAll,
  float* __restrict__ sr)
{
  __shared__ _Float16 buf[32768];   // 64KB: A=buf[0..16383], B=buf[16384..]
  const int t = threadIdx.x;
  const int lane = t & 63;
  const int w = __builtin_amdgcn_readfirstlane(t >> 6);   // 0..7
  const int p31 = lane & 31; const int hi = lane >> 5;

  // ---- z build into A: thread (p = t&127, q = t>>7) ----
  {
    const int p = t & 127; const int q = t >> 7;
    const int px = blockIdx.x*128 + p;
    const int y = px / HWD; const int x = px - y*HWD;
    float lx = (x+0.5f)*0.25f - 0.5f;
    float ly = (y+0.5f)*0.25f - 0.5f;
    float cxf = fminf(fmaxf(rintf(lx),0.f),95.f);
    float cyf = fminf(fmaxf(rintf(ly),0.f),95.f);
    int base = (int)cyf*LWI + (int)cxf;
    auto zwrite = [&](int k, float v){
      buf[((k>>4)*4 + (p>>5))*512 + ((p&31) + 32*((k>>3)&1))*8 + (k&7)] = (_Float16)v;
    };
    if (q < 2){
      #pragma unroll
      for (int j=0;j<32;++j){ int c=q*32+j; zwrite(c, feat[c*LRPIX+base]); }
    } else if (q == 2){
      float xn = (x+0.5f)/384.0f*2.0f - 1.0f;
      float s = sinf(xn*3.14159265358979323846f);
      float c = cosf(xn*3.14159265358979323846f);
      #pragma unroll
      for (int b=0;b<10;++b){
        zwrite(64+4*b+0, s); zwrite(64+4*b+1, c);
        float s2 = 2.f*s*c; float c2 = 1.f - 2.f*s*s;
        s=s2; c=c2;
      }
      zwrite(104, lx-cxf); zwrite(105, ly-cyf);
    } else {
      float yn = (y+0.5f)/384.0f*2.0f - 1.0f;
      float s = sinf(yn*3.14159265358979323846f);
      float c = cosf(yn*3.14159265358979323846f);
      #pragma unroll
      for (int b=0;b<10;++b){
        zwrite(64+4*b+2, s); zwrite(64+4*b+3, c);
        float s2 = 2.f*s*c; float c2 = 1.f - 2.f*s*s;
        s=s2; c=c2;
      }
      #pragma unroll
      for (int k=106;k<112;++k) zwrite(k, 0.f);
    }
  }
  __syncthreads();

  const int WOFF[6] = {0,28672,94208,159744,225280,290816};
  _Float16* cur = buf;            // layer input
  _Float16* nxt = buf + 16384;    // layer output

  // ---- 5 hidden layers: MFMA(cur) -> EPI writes nxt (no barrier between!) ----
  #pragma unroll 1
  for (int L=0; L<5; ++L){
    const _Float16* Wl = WB + WOFF[L];
    const int nks = (L==0)?7:16;
    f32x16 acc[4] = {f32x16{},f32x16{},f32x16{},f32x16{}};
    for (int ks=0; ks<nks; ++ks){
      f16x8 a = *(const f16x8*)(Wl + (ks*8+w)*512 + lane*8);
      const _Float16* bp = cur + ks*2048 + lane*8;
      f16x8 b0 = *(const f16x8*)(bp);
      f16x8 b1 = *(const f16x8*)(bp + 512);
      f16x8 b2 = *(const f16x8*)(bp + 1024);
      f16x8 b3 = *(const f16x8*)(bp + 1536);
      acc[0] = __builtin_amdgcn_mfma_f32_32x32x16_f16(a,b0,acc[0],0,0,0);
      acc[1] = __builtin_amdgcn_mfma_f32_32x32x16_f16(a,b1,acc[1],0,0,0);
      acc[2] = __builtin_amdgcn_mfma_f32_32x32x16_f16(a,b2,acc[2],0,0,0);
      acc[3] = __builtin_amdgcn_mfma_f32_32x32x16_f16(a,b3,acc[3],0,0,0);
    }
    // EPI: gelu (packed f16 tail) -> nxt. nxt's old contents are dead this layer.
    const float* Bl = biasAll + L*256;
    #pragma unroll
    for (int q2=0;q2<4;++q2){
      float4 bs = *(const float4*)&Bl[w*32 + q2*8 + 4*hi];
      _Float16* dst = nxt + ((w*2+(q2>>1))*4)*512 + (p31 + 32*(q2&1))*8 + 4*hi;
      #pragma unroll
      for (int pb=0;pb<4;++pb){
        f16x4 o;
        gelu2pk(acc[pb][q2*4+0] + bs.x, acc[pb][q2*4+1] + bs.y, (_Float16*)&o);
        gelu2pk(acc[pb][q2*4+2] + bs.z, acc[pb][q2*4+3] + bs.w, ((_Float16*)&o)+2);
        *(f16x4*)(dst + pb*512) = o;
      }
    }
    __syncthreads();           // single barrier per layer
    _Float16* tmp = cur; cur = nxt; nxt = tmp;
  }
  // after L0..L4: cur == buf+16384 (h5)

  // ---- heads: K=256 -> 200 rows; klog f16 overlay [200][132] over whole buf ----
  {
    f32x16 acc[4] = {f32x16{},f32x16{},f32x16{},f32x16{}};
    if (w < 7){
      const _Float16* Wl = WB + WOFF[5];
      for (int ks=0; ks<16; ++ks){
        f16x8 a = *(const f16x8*)(Wl + (ks*8+w)*512 + lane*8);
        const _Float16* bp = cur + ks*2048 + lane*8;
        f16x8 b0 = *(const f16x8*)(bp);
        f16x8 b1 = *(const f16x8*)(bp + 512);
        f16x8 b2 = *(const f16x8*)(bp + 1024);
        f16x8 b3 = *(const f16x8*)(bp + 1536);
        acc[0] = __builtin_amdgcn_mfma_f32_32x32x16_f16(a,b0,acc[0],0,0,0);
        acc[1] = __builtin_amdgcn_mfma_f32_32x32x16_f16(a,b1,acc[1],0,0,0);
        acc[2] = __builtin_amdgcn_mfma_f32_32x32x16_f16(a,b2,acc[2],0,0,0);
        acc[3] = __builtin_amdgcn_mfma_f32_32x32x16_f16(a,b3,acc[3],0,0,0);
      }
    }
    __syncthreads();   // all reads of h5 done before overlay overwrites
    if (w < 7){
      #pragma unroll
      for (int reg=0;reg<16;++reg){
        int f = w*32 + (reg&3) + 8*(reg>>2) + 4*hi;
        if (f < 200){
          float bias = biasAll[1280 + f];
          #pragma unroll
          for (int pb=0;pb<4;++pb)
            buf[f*132 + pb*32 + p31] = (_Float16)(acc[pb][reg] + bias);
        }
      }
    }
  }
  __syncthreads();

  // ---- softmax per head + gate softmax; all 512 threads (p, hd) ----
  {
    const int p = t & 127; const int hd = t >> 7;
    auto KL = [&](int col)->float { return (float)buf[col*132 + p]; };
    const float L2E = 1.4426950408889634f;
    float g0=KL(196),g1=KL(197),g2=KL(198),g3=KL(199);
    float gm = fmaxf(fmaxf(g0,g1),fmaxf(g2,g3));
    float e0=exp2f((g0-gm)*L2E),e1=exp2f((g1-gm)*L2E),
          e2=exp2f((g2-gm)*L2E),e3=exp2f((g3-gm)*L2E);
    float gate = ((hd==0)?e0:(hd==1)?e1:(hd==2)?e2:e3)/(e0+e1+e2+e3);
    float m = -1e30f;
    #pragma unroll
    for (int k=0;k<49;++k) m = fmaxf(m, KL(hd*49+k));
    float s = 0.f;
    float ev[49];
    #pragma unroll
    for (int k=0;k<49;++k){ float e=exp2f((KL(hd*49+k)-m)*L2E); s+=e; ev[k]=e; }
    float sc = gate/s;
    #pragma unroll
    for (int k=0;k<49;++k) buf[(hd*49+k)*132 + p] = (_Float16)(ev[k]*sc);
  }
  __syncthreads();

  // ---- apply mixed 7x7 kernel ----
  if (t < 384){
    const int c = t >> 7; const int p = t & 127;
    const int px = blockIdx.x*128 + p;
    const int y = px / HWD; const int x = px - y*HWD;
    float lx = (x+0.5f)*0.25f - 0.5f;
    float ly = (y+0.5f)*0.25f - 0.5f;
    int cxi = (int)fminf(fmaxf(rintf(lx),0.f),95.f);
    int cyi = (int)fminf(fmaxf(rintf(ly),0.f),95.f);
    const float* lrc = lr + c*LRPIX;
    float acc = 0.f;
    #pragma unroll
    for (int k=0;k<49;++k){
      float km = (float)buf[k*132+p] + (float)buf[(49+k)*132+p]
               + (float)buf[(98+k)*132+p] + (float)buf[(147+k)*132+p];
      int oy = k/7 - 3, ox = k - (k/7)*7 - 3;
      int nyy = min(max(cyi+oy,0),95), nxx = min(max(cxi+ox,0),95);
      acc = fmaf(km, lrc[nyy*LWI+nxx], acc);
    }
    sr[c*NPIX + px] = acc;
  }
}

// ---- refiner v2: one block per (16x16 tile, group); groups independent ----
__global__ __launch_bounds__(256) void refiner_group_kernel(
  const float* __restrict__ lr, const float* __restrict__ srg,
  const float* __restrict__ w0, const float* __restrict__ b0,
  const float* __restrict__ w1, const float* __restrict__ b1,
  const float* __restrict__ w2, const float* __restrict__ b2,
  float* __restrict__ resW)
{
  __shared__ float x6s[2][22][26];
  __shared__ float r1a[16][20][20];
  __shared__ float r1b[16][18][20];
  const int g = blockIdx.z;
  const int tid = threadIdx.x;
  const int gx0 = blockIdx.x*16, gy0 = blockIdx.y*16;

  for (int i = tid; i < 2*22*22; i += 256){
    int ic = i / 484; int rem = i - ic*484; int yy = rem / 22; int xx = rem - yy*22;
    int ch = g*2 + ic;
    int gy = gy0 - 3 + yy, gx = gx0 - 3 + xx;
    float v = 0.f;
    if (gy>=0 && gy<HWD && gx>=0 && gx<HWD){
      int c = (ch<3)?ch:(ch-3);
      float lu = lr_up_at(lr, c, gy, gx);
      v = (ch < 3) ? lu : (srg[c*NPIX + gy*HWD + gx] - lu);
    }
    x6s[ic][yy][xx] = v;
  }
  __syncthreads();

  for (int task = tid; task < 320; task += 256){
    int o = task / 20; int yy = task - o*20;
    int og = g*16 + o;
    float bias = b0[og];
    float acc[20];
    #pragma unroll
    for (int j=0;j<20;++j) acc[j] = bias;
    #pragma unroll
    for (int ic=0; ic<2; ++ic){
      #pragma unroll
      for (int dyy=0; dyy<3; ++dyy){
        float row[22];
        #pragma unroll
        for (int j=0;j<22;++j) row[j] = x6s[ic][yy+dyy][j];
        #pragma unroll
        for (int dxx=0; dxx<3; ++dxx){
          float wv = w0[((og*2+ic)*3+dyy)*3+dxx];
          #pragma unroll
          for (int j=0;j<20;++j) acc[j] = fmaf(wv, row[j+dxx], acc[j]);
        }
      }
    }
    int gyy = gy0 - 2 + yy;
    bool rok = (gyy>=0 && gyy<HWD);
    #pragma unroll
    for (int j=0;j<20;++j){
      int gxx = gx0 - 2 + j;
      r1a[o][yy][j] = (rok && gxx>=0 && gxx<HWD) ? gelu_f(acc[j]) : 0.f;
    }
  }
  __syncthreads();

  for (int task = tid; task < 288; task += 256){
    int o = task / 18; int yy = task - o*18;
    int og = g*16 + o;
    float bias = b1[og];
    float acc[18];
    #pragma unroll
    for (int j=0;j<18;++j) acc[j] = bias;
    for (int ic=0; ic<16; ++ic){
      #pragma unroll
      for (int dyy=0; dyy<3; ++dyy){
        float row[20];
        #pragma unroll
        for (int q=0;q<5;++q)
          *(float4*)&row[q*4] = *(const float4*)&r1a[ic][yy+dyy][q*4];
        #pragma unroll
        for (int dxx=0; dxx<3; ++dxx){
          float wv = w1[((og*16+ic)*3+dyy)*3+dxx];
          #pragma unroll
          for (int j=0;j<18;++j) acc[j] = fmaf(wv, row[j+dxx], acc[j]);
        }
      }
    }
    int gyy = gy0 - 1 + yy;
    bool rok = (gyy>=0 && gyy<HWD);
    #pragma unroll
    for (int j=0;j<18;++j){
      int gxx = gx0 - 1 + j;
      r1b[o][yy][j] = (rok && gxx>=0 && gxx<HWD) ? gelu_f(acc[j]) : 0.f;
    }
  }
  __syncthreads();

  {
    int ty = tid >> 4, tx = tid & 15;
    float a = b2[g];
    for (int ic=0; ic<16; ++ic){
      #pragma unroll
      for (int dyy=0; dyy<3; ++dyy){
        #pragma unroll
        for (int dxx=0; dxx<3; ++dxx){
          a = fmaf(w2[((g*16+ic)*3+dyy)*3+dxx], r1b[ic][ty+dyy][tx+dxx], a);
        }
      }
    }
    resW[g*NPIX + (gy0+ty)*HWD + gx0+tx] = a;
  }
}

// gray-residual fusion: out = clip(lr_up + gray(sr+res) - gray(lr_up))
__global__ __launch_bounds__(256) void fuse_kernel(
  const float* __restrict__ lr, const float* __restrict__ srg,
  const float* __restrict__ resW, float* __restrict__ out)
{
  int p = blockIdx.x*256 + threadIdx.x;
  int y = p / HWD, x = p - y*HWD;
  float lu[3];
  float d = 0.f;
  const float cf0=0.2989f, cf1=0.587f, cf2=0.114f;
  lu[0] = lr_up_at(lr, 0, y, x);
  lu[1] = lr_up_at(lr, 1, y, x);
  lu[2] = lr_up_at(lr, 2, y, x);
  d += cf0*(srg[0*NPIX+p] + resW[0*NPIX+p] - lu[0]);
  d += cf1*(srg[1*NPIX+p] + resW[1*NPIX+p] - lu[1]);
  d += cf2*(srg[2*NPIX+p] + resW[2*NPIX+p] - lu[2]);
  #pragma unroll
  for (int c=0;c<3;++c){
    float o_ = lu[c] + d;
    out[c*NPIX + p] = fminf(fmaxf(o_, 0.f), 1.f);
  }
}

extern "C" void kernel_launch(void* const* d_in, const int* in_sizes, int n_in,
                              void* d_out, int out_size, void* d_ws, size_t ws_size,
                              hipStream_t stream){
  const float* lr  = (const float*)d_in[0];
  const float* ew0 = (const float*)d_in[1];  const float* eb0 = (const float*)d_in[2];
  const float* ew1 = (const float*)d_in[3];  const float* eb1 = (const float*)d_in[4];
  const float* ew2 = (const float*)d_in[5];  const float* eb2 = (const float*)d_in[6];
  const float* ew3 = (const float*)d_in[7];  const float* eb3 = (const float*)d_in[8];
  const float* cw0 = (const float*)d_in[9];  const float* cb0 = (const float*)d_in[10];
  const float* cw1 = (const float*)d_in[11]; const float* cb1 = (const float*)d_in[12];
  const float* mw0 = (const float*)d_in[13]; const float* mb0 = (const float*)d_in[14];
  const float* mw1 = (const float*)d_in[15]; const float* mb1 = (const float*)d_in[16];
  const float* mw2 = (const float*)d_in[17]; const float* mb2 = (const float*)d_in[18];
  const float* mw3 = (const float*)d_in[19]; const float* mb3 = (const float*)d_in[20];
  const float* mw4 = (const float*)d_in[21]; const float* mb4 = (const float*)d_in[22];
  const float* hkw = (const float*)d_in[23]; const float* hkb = (const float*)d_in[24];
  const float* hgw = (const float*)d_in[25]; const float* hgb = (const float*)d_in[26];
  const float* rw0 = (const float*)d_in[27]; const float* rb0 = (const float*)d_in[28];
  const float* rw1 = (const float*)d_in[29]; const float* rb1 = (const float*)d_in[30];
  const float* rw2 = (const float*)d_in[31]; const float* rb2 = (const float*)d_in[32];

  float* ws = (float*)d_ws;
  float* f0  = ws;                     // [64][96][96]; reused as resW after convs
  float* f1  = ws + 589824;            // [64][96][96]
  float* srp = ws + 2*589824;          // [3][384][384]
  _Float16* WB = (_Float16*)(ws + 1622016);   // 356352 f16
  float* biasAll = ws + 1622016 + 178176;     // 1536 f32
  float* resW = f0;                    // free after conv1x1 chain

  pack_weights<<<1398,256,0,stream>>>(mw0,mw1,mw2,mw3,mw4,hkw,hgw,
      mb0,mb1,mb2,mb3,mb4,hkb,hgb, WB, biasAll);

  conv3x3_kernel<<<2304,256,0,stream>>>(lr, ew0, eb0, f0, 3);
  conv3x3_tiled64<<<dim3(12,12,4),256,0,stream>>>(f0, ew1, eb1, f1);
  conv3x3_tiled64<<<dim3(12,12,4),256,0,stream>>>(f1, ew2, eb2, f0);
  conv3x3_tiled64<<<dim3(12,12,4),256,0,stream>>>(f0, ew3, eb3, f1);
  conv1x1_kernel<<<2304,256,0,stream>>>(f1, cw0, cb0, f0, 66, 1);
  conv1x1_kernel<<<2304,256,0,stream>>>(f0, cw1, cb1, f1, 64, 0);

  mlp_mfma4_kernel<<<1152,512,0,stream>>>(f1, lr, WB, biasAll, srp);

  refiner_group_kernel<<<dim3(24,24,3),256,0,stream>>>(lr, srp,
      rw0,rb0, rw1,rb1, rw2,rb2, resW);
  fuse_kernel<<<576,256,0,stream>>>(lr, srp, resW, (float*)d_out);
}